// Round 10
// baseline (155.704 us; speedup 1.0000x reference)
//
#include <hip/hip_runtime.h>
#include <hip/hip_bf16.h>
#include <math.h>

// Masked dot-product attention, bf16 MFMA flash kernel, round 13.
// B=32, LQ=LK=2048, D=64. S^T = K*Q^T and O^T = V^T*P^T with 32x32x16 MFMA.
// NEW vs round 12:
//  - LDS-free LPT rank (shfl+ballot, no __shared__ s_b): round-12's 4-byte
//    shared var pushed LDS 32768->33280 -> resident cap 5->4 blocks/CU.
//    Restores 5 blocks/CU (20-wave cap) and drops the extra prologue barrier.
//  - Staging reorder: pack K/V to bf16 regs FIRST, then issue t+1 prefetch,
//    then LDS writes, then barrier. The prefetch drain at the barrier now
//    overlaps the write phase instead of exposing full L2/HBM latency.
//  - s_setprio(1) around QK and PV MFMA clusters (T5: multi-block blocks at
//    independent phases -> scheduler favors MFMA-entering waves, +4-7% attn).

#define B_    32
#define LQ_   2048
#define LK_   2048
#define D_    64

typedef __attribute__((ext_vector_type(8)))  short bf16x8;
typedef __attribute__((ext_vector_type(4)))  float f32x4;
typedef __attribute__((ext_vector_type(16))) float f32x16;
typedef __attribute__((ext_vector_type(2)))  unsigned u32x2;

static __device__ __forceinline__ unsigned pk_bf16(float a, float b) {
    __hip_bfloat162 h = __float22bfloat162_rn(float2{a, b});
    return *(unsigned*)&h;   // x in low 16 bits, y in high
}

// v_permlane32_swap_b32 via builtin (hazard-safe). Semantics: swaps the high
// 32 lanes of the first operand with the low 32 lanes of the second.
// r[0] = {a.lanes[0:31], b.lanes[0:31]}, r[1] = {a.lanes[32:63], b.lanes[32:63]}.
static __device__ __forceinline__ u32x2 plswap(unsigned a, unsigned b) {
    return __builtin_amdgcn_permlane32_swap(a, b, false, false);
}
// cross-half (lane ^ 32) reduce helpers (orientation-invariant: a == b)
static __device__ __forceinline__ float xhalf_max(float x) {
    u32x2 r = plswap(__float_as_uint(x), __float_as_uint(x));
    return fmaxf(__uint_as_float(r[0]), __uint_as_float(r[1]));
}
static __device__ __forceinline__ float xhalf_add(float x) {
    u32x2 r = plswap(__float_as_uint(x), __float_as_uint(x));
    return __uint_as_float(r[0]) + __uint_as_float(r[1]);
}

// ---------------------------------------------------------------------------
// Pass 1: per-(qblock=128 rows, batch, split) flash attention over [t0, t1).
// 256 threads = 4 q-waves sharing one double-buffered 64x64 K/V LDS tile.
// LPT: blockIdx.x -> (batch_rank, qblock, split); batch = rank-th longest vl,
// computed per-wave with shfl+ballot (no LDS, no barrier).
// Writes UNNORMALIZED O^T partial + (m, l) per q row.
// ---------------------------------------------------------------------------
template<int NS>
__global__ __launch_bounds__(256, 2) void fa_split7_kernel(
    const float* __restrict__ Q, const float* __restrict__ K,
    const float* __restrict__ V, const int* __restrict__ vlen,
    float* __restrict__ OP, float* __restrict__ ML)
{
    __shared__ __align__(16) short Kl[2][64 * 64];
    __shared__ __align__(16) short Vt[2][64 * 64];

    const int tid  = threadIdx.x;          // 0..255
    const int wid  = tid >> 6;             // 0..3  (q sub-block)
    const int lane = tid & 63;
    const int c31  = lane & 31;
    const int h    = lane >> 5;

    // ---- LPT remap (LDS-free): rank batches by vl DESC, index tie-break ----
    constexpr int PB = 16 * NS;            // blocks per batch (16,32,64)
    const int L    = blockIdx.x;
    const int rank = L / PB;               // compile-time divisor
    const int sub  = L % PB;
    const int qb   = sub & 15;
    const int s    = sub >> 4;
    int b;
    {
        const int vj = vlen[c31];          // lanes j and j+32 hold vlen[j]
        int r = 0;
#pragma unroll
        for (int k = 0; k < 32; ++k) {
            const int vk = __shfl(vj, k);  // broadcast vlen[k]
            r += (vk > vj) || (vk == vj && k < c31);
        }
        const unsigned long long match = __ballot(r == rank);
        b = (int)(__ffsll((unsigned long long)match) - 1) & 31;
    }
    const int q0 = qb * 128 + wid * 32;
    const int vl = vlen[b];
    const int nt    = (vl + 63) >> 6;
    const int chunk = (nt + NS - 1) / NS;
    const int t0    = s * chunk;
    const int t1    = min(t0 + chunk, nt);

    const float qscale = 0.125f * 1.44269504088896340736f;  // 1/sqrt(64)*log2(e)

    // ---- Q B-frags in registers: B[k=dim][n=q], dim = ks*16 + h*8 + j ----
    unsigned qfrag[4][4];
#pragma unroll
    for (int ks = 0; ks < 4; ++ks) {
        const float* qp = Q + ((size_t)(b * LQ_ + q0 + c31)) * D_ + ks * 16 + h * 8;
        f32x4 t0v = *(const f32x4*)qp;
        f32x4 t1v = *(const f32x4*)(qp + 4);
#pragma unroll
        for (int jj = 0; jj < 2; ++jj) {
            qfrag[ks][jj]     = pk_bf16(t0v[2*jj] * qscale, t0v[2*jj+1] * qscale);
            qfrag[ks][jj + 2] = pk_bf16(t1v[2*jj] * qscale, t1v[2*jj+1] * qscale);
        }
    }

    f32x16 oacc[2];     // O^T acc: dim row = dt*32 + (r&3)+8*(r>>2)+4h, col q = c31
#pragma unroll
    for (int dt = 0; dt < 2; ++dt)
#pragma unroll
        for (int r = 0; r < 16; ++r) oacc[dt][r] = 0.f;
    float mrun = -INFINITY, lrun = 0.f;

    // ---- staging maps (256 threads stage the whole 64x64 K and V tiles) ----
    const int skey = tid >> 2, skh = tid & 3;          // K: quarter-row each
    const int vkg = tid >> 4, vdg = tid & 15;          // V: 4 keys x 4 dims

    const float* kgp = K + ((size_t)(b * LK_ + skey)) * D_ + skh * 16;
    const float* vgp = V + ((size_t)(b * LK_ + vkg * 4)) * D_ + vdg * 4;

    f32x4 kr[4], vr[4];
    // ---- prologue: prefetch tile t0 into registers ----
    if (t0 < t1) {
        const size_t off = (size_t)t0 * 64 * D_;
#pragma unroll
        for (int i = 0; i < 4; ++i) kr[i] = *(const f32x4*)(kgp + off + 4 * i);
#pragma unroll
        for (int i = 0; i < 4; ++i) vr[i] = *(const f32x4*)(vgp + off + (size_t)i * D_);
    }

    for (int t = t0; t < t1; ++t) {
        const int k0 = t * 64;
        const int buf = t & 1;

        // ---- pack tile t to bf16 in regs (frees kr/vr for the prefetch) ----
        unsigned pk32[8], vw[8];
#pragma unroll
        for (int m = 0; m < 8; ++m)
            pk32[m] = pk_bf16(kr[m >> 1][2 * (m & 1)], kr[m >> 1][2 * (m & 1) + 1]);
#pragma unroll
        for (int dr = 0; dr < 4; ++dr) {
            vw[2 * dr]     = pk_bf16(vr[0][dr], vr[1][dr]);
            vw[2 * dr + 1] = pk_bf16(vr[2][dr], vr[3][dr]);
        }
        // ---- issue prefetch for tile t+1 NOW; the LDS-write phase below
        //      runs while the loads are in flight (drained at the barrier) ----
        if (t + 1 < t1) {
            const float* kn = kgp + (size_t)(k0 + 64) * D_;
            const float* vn = vgp + (size_t)(k0 + 64) * D_;
#pragma unroll
            for (int i = 0; i < 4; ++i) kr[i] = *(const f32x4*)(kn + 4 * i);
#pragma unroll
            for (int i = 0; i < 4; ++i) vr[i] = *(const f32x4*)(vn + (size_t)i * D_);
        }
        // ---- LDS writes from packed regs ----
#pragma unroll
        for (int cch = 0; cch < 2; ++cch) {
            const int pos = (skh * 2 + cch) ^ (skey & 7);
            *(bf16x8*)&Kl[buf][skey * 64 + pos * 8] = *(bf16x8*)&pk32[4 * cch];
        }
#pragma unroll
        for (int dr = 0; dr < 4; ++dr) {
            const int dim = vdg * 4 + dr;
            const int pos = (vkg >> 1) ^ (dim & 7);
            *(uint2*)&Vt[buf][dim * 64 + pos * 8 + (vkg & 1) * 4] =
                uint2{vw[2 * dr], vw[2 * dr + 1]};
        }
        __syncthreads();

        // ---- S^T = K * Q^T : 2 key-tiles x 4 k-steps of 32x32x16 ----
        f32x16 st[2];
        __builtin_amdgcn_s_setprio(1);
#pragma unroll
        for (int ss = 0; ss < 2; ++ss) {
#pragma unroll
            for (int r = 0; r < 16; ++r) st[ss][r] = 0.f;
#pragma unroll
            for (int ks = 0; ks < 4; ++ks) {
                const int pos = (ks * 2 + h) ^ (c31 & 7);
                bf16x8 kf = *(const bf16x8*)&Kl[buf][(ss * 32 + c31) * 64 + pos * 8];
                st[ss] = __builtin_amdgcn_mfma_f32_32x32x16_bf16(
                    kf, *(const bf16x8*)&qfrag[ks][0], st[ss], 0, 0, 0);
            }
        }
        __builtin_amdgcn_s_setprio(0);

        // ---- mask tail keys >= vl ----
        if (k0 + 64 > vl) {
#pragma unroll
            for (int ss = 0; ss < 2; ++ss) {
                const int base = k0 + ss * 32 + 4 * h;
#pragma unroll
                for (int r = 0; r < 16; ++r) {
                    const int key = base + (r & 3) + 8 * (r >> 2);
                    if (key >= vl) st[ss][r] = -1e30f;
                }
            }
        }

        // ---- online softmax (log2 domain), defer-max; tree reductions ----
        float m8[8];
#pragma unroll
        for (int r = 0; r < 8; ++r)
            m8[r] = fmaxf(fmaxf(st[0][r], st[0][r + 8]),
                          fmaxf(st[1][r], st[1][r + 8]));
#pragma unroll
        for (int o = 4; o; o >>= 1)
#pragma unroll
            for (int r = 0; r < o; ++r) m8[r] = fmaxf(m8[r], m8[r + o]);
        const float tm = xhalf_max(m8[0]);

        if (__any(tm > mrun + 8.f)) {          // rare after the first tile
            const float mnew = fmaxf(mrun, tm);
            const float corr = exp2f(mrun - mnew);
            lrun *= corr;
#pragma unroll
            for (int dt = 0; dt < 2; ++dt)
#pragma unroll
                for (int r = 0; r < 16; ++r) oacc[dt][r] *= corr;
            mrun = mnew;
        }
#pragma unroll
        for (int ss = 0; ss < 2; ++ss)
#pragma unroll
            for (int r = 0; r < 16; ++r)
                st[ss][r] = exp2f(st[ss][r] - mrun);   // bounded by 2^8
        float s8[8];
#pragma unroll
        for (int r = 0; r < 8; ++r)
            s8[r] = (st[0][r] + st[0][r + 8]) + (st[1][r] + st[1][r + 8]);
#pragma unroll
        for (int o = 4; o; o >>= 1)
#pragma unroll
            for (int r = 0; r < o; ++r) s8[r] += s8[r + o];
        lrun += xhalf_add(s8[0]);

        // ---- pack P to bf16 pairs ----
        unsigned pk[2][8];
#pragma unroll
        for (int ss = 0; ss < 2; ++ss)
#pragma unroll
            for (int m = 0; m < 8; ++m)
                pk[ss][m] = pk_bf16(st[ss][2 * m], st[ss][2 * m + 1]);

        // ---- O^T += V^T * P^T : 4 k-steps x 2 dim-tiles ----
        //  P fragment exchange: r = plswap(p0, p2) -> r[0] = {p0.low, p2.low}
        //  = pf0, r[1] = {p0.high, p2.high} = pf2.
        __builtin_amdgcn_s_setprio(1);
#pragma unroll
        for (int kq = 0; kq < 4; ++kq) {
            const int ss = kq >> 1, A4 = (kq & 1) * 4;
            u32x2 r02 = plswap(pk[ss][A4],     pk[ss][A4 + 2]);
            u32x2 r13 = plswap(pk[ss][A4 + 1], pk[ss][A4 + 3]);
            unsigned pf[4] = {r02[0], r13[0], r02[1], r13[1]};
            const bf16x8 pfr = *(const bf16x8*)&pf[0];
#pragma unroll
            for (int dt = 0; dt < 2; ++dt) {
                const int pos = (kq * 2 + h) ^ (c31 & 7);
                bf16x8 vf = *(const bf16x8*)&Vt[buf][(dt * 32 + c31) * 64 + pos * 8];
                oacc[dt] = __builtin_amdgcn_mfma_f32_32x32x16_bf16(vf, pfr, oacc[dt], 0, 0, 0);
            }
        }
        __builtin_amdgcn_s_setprio(0);
    }

    // ---- epilogue: store UNNORMALIZED partial O^T and (m, l) ----
    const size_t row = (size_t)s * (B_ * LQ_) + b * LQ_ + q0 + c31;
    float* op = OP + row * D_;
#pragma unroll
    for (int dt = 0; dt < 2; ++dt)
#pragma unroll
        for (int g = 0; g < 4; ++g) {
            f32x4 v;
#pragma unroll
            for (int j = 0; j < 4; ++j) v[j] = oacc[dt][4 * g + j];
            *(f32x4*)(op + dt * 32 + 8 * g + 4 * h) = v;
        }
    if (h == 0)
        *(float2*)&ML[row * 2] = float2{mrun, lrun};   // (-inf, 0) if empty split
}

// ---------------------------------------------------------------------------
// Pass 2: merge NS partials per q row. One thread per (row, 4-dim chunk).
// ---------------------------------------------------------------------------
template<int NS>
__global__ __launch_bounds__(256) void fa_merge_kernel(
    const float* __restrict__ OP, const float* __restrict__ ML,
    float* __restrict__ O)
{
    const int g   = blockIdx.x * 256 + threadIdx.x;   // 0 .. B*LQ*16-1
    const int row = g >> 4;                            // b*LQ + q
    const int qd  = (g & 15) * 4;

    float mf = -INFINITY;
#pragma unroll
    for (int s = 0; s < NS; ++s) {
        float2 ml = *(const float2*)&ML[((size_t)s * (B_ * LQ_) + row) * 2];
        mf = fmaxf(mf, ml.x);                          // split 0 always finite
    }
    float den = 0.f;
    f32x4 acc = {0.f, 0.f, 0.f, 0.f};
#pragma unroll
    for (int s = 0; s < NS; ++s) {
        const size_t srow = (size_t)s * (B_ * LQ_) + row;
        float2 ml = *(const float2*)&ML[srow * 2];
        const float c = exp2f(ml.x - mf);              // 0 for empty splits
        den += c * ml.y;
        f32x4 v = *(const f32x4*)&OP[srow * D_ + qd];
        acc += v * c;                                  // empty split: c=0, v=0
    }
    const float inv = 1.f / den;
    *(f32x4*)(O + (size_t)row * D_ + qd) = acc * inv;
}

// ---------------------------------------------------------------------------
// Fallback: monolithic kernel (round-3 structure + defer-max), no workspace.
// ---------------------------------------------------------------------------
__global__ __launch_bounds__(128, 2) void fa_mono_kernel(
    const float* __restrict__ Q, const float* __restrict__ K,
    const float* __restrict__ V, const int* __restrict__ vlen,
    float* __restrict__ O)
{
    __shared__ __align__(16) short Kl[2][64 * 64];
    __shared__ __align__(16) short Vt[2][64 * 64];

    const int tid  = threadIdx.x;
    const int wave = tid >> 6;
    const int lane = tid & 63;
    const int c31  = lane & 31;
    const int h    = lane >> 5;

    const int b  = blockIdx.y;
    const int q0 = blockIdx.x * 64 + wave * 32;
    const int vl = vlen[b];
    const int nt = (vl + 63) >> 6;

    const float qscale = 0.125f * 1.44269504088896340736f;

    unsigned qfrag[4][4];
#pragma unroll
    for (int ks = 0; ks < 4; ++ks) {
        const float* qp = Q + ((size_t)(b * LQ_ + q0 + c31)) * D_ + ks * 16 + h * 8;
        f32x4 t0 = *(const f32x4*)qp;
        f32x4 t1 = *(const f32x4*)(qp + 4);
#pragma unroll
        for (int jj = 0; jj < 2; ++jj) {
            qfrag[ks][jj]     = pk_bf16(t0[2*jj] * qscale, t0[2*jj+1] * qscale);
            qfrag[ks][jj + 2] = pk_bf16(t1[2*jj] * qscale, t1[2*jj+1] * qscale);
        }
    }

    f32x16 oacc[2];
#pragma unroll
    for (int dt = 0; dt < 2; ++dt)
#pragma unroll
        for (int r = 0; r < 16; ++r) oacc[dt][r] = 0.f;
    float mrun = -INFINITY, lrun = 0.f;

    const int skey = tid >> 1, skh = tid & 1;
    const int vkg = tid >> 4, vdg = tid & 15;

    const float* kgp = K + ((size_t)(b * LK_ + skey)) * D_ + skh * 32;
    const float* vgp = V + ((size_t)(b * LK_ + vkg * 8)) * D_ + vdg * 4;

    f32x4 kr[8], vr[8];
#pragma unroll
    for (int i = 0; i < 8; ++i) kr[i] = *(const f32x4*)(kgp + 4 * i);
#pragma unroll
    for (int i = 0; i < 8; ++i) vr[i] = *(const f32x4*)(vgp + (size_t)i * D_);

    for (int t = 0; t < nt; ++t) {
        const int k0 = t * 64;
        const int buf = t & 1;
        {
            unsigned pk32[16];
#pragma unroll
            for (int m = 0; m < 16; ++m)
                pk32[m] = pk_bf16(kr[m >> 1][2 * (m & 1)], kr[m >> 1][2 * (m & 1) + 1]);
#pragma unroll
            for (int cch = 0; cch < 4; ++cch) {
                const int pos = (skh * 4 + cch) ^ (skey & 7);
                *(bf16x8*)&Kl[buf][skey * 64 + pos * 8] = *(bf16x8*)&pk32[4 * cch];
            }
#pragma unroll
            for (int dr = 0; dr < 4; ++dr) {
                unsigned w[4];
#pragma unroll
                for (int p = 0; p < 4; ++p)
                    w[p] = pk_bf16(vr[2 * p][dr], vr[2 * p + 1][dr]);
                const int dim = vdg * 4 + dr;
                const int pos = vkg ^ (dim & 7);
                *(bf16x8*)&Vt[buf][dim * 64 + pos * 8] = *(bf16x8*)&w[0];
            }
        }
        if (t + 1 < nt) {
            const float* kn = kgp + (size_t)(k0 + 64) * D_;
            const float* vn = vgp + (size_t)(k0 + 64) * D_;
#pragma unroll
            for (int i = 0; i < 8; ++i) kr[i] = *(const f32x4*)(kn + 4 * i);
#pragma unroll
            for (int i = 0; i < 8; ++i) vr[i] = *(const f32x4*)(vn + (size_t)i * D_);
        }
        __syncthreads();

        f32x16 st[2];
#pragma unroll
        for (int ss = 0; ss < 2; ++ss) {
#pragma unroll
            for (int r = 0; r < 16; ++r) st[ss][r] = 0.f;
#pragma unroll
            for (int ks = 0; ks < 4; ++ks) {
                const int pos = (ks * 2 + h) ^ (c31 & 7);
                bf16x8 kf = *(const bf16x8*)&Kl[buf][(ss * 32 + c31) * 64 + pos * 8];
                st[ss] = __builtin_amdgcn_mfma_f32_32x32x16_bf16(
                    kf, *(const bf16x8*)&qfrag[ks][0], st[ss], 0, 0, 0);
            }
        }
        if (k0 + 64 > vl) {
#pragma unroll
            for (int ss = 0; ss < 2; ++ss) {
                const int base = k0 + ss * 32 + 4 * h;
#pragma unroll
                for (int r = 0; r < 16; ++r) {
                    const int key = base + (r & 3) + 8 * (r >> 2);
                    if (key >= vl) st[ss][r] = -1e30f;
                }
            }
        }
        float tm = st[0][0];
#pragma unroll
        for (int ss = 0; ss < 2; ++ss)
#pragma unroll
            for (int r = 0; r < 16; ++r) tm = fmaxf(tm, st[ss][r]);
        tm = fmaxf(tm, __shfl_xor(tm, 32));
        if (__any(tm > mrun + 8.f)) {
            const float mnew = fmaxf(mrun, tm);
            const float corr = exp2f(mrun - mnew);
            lrun *= corr;
#pragma unroll
            for (int dt = 0; dt < 2; ++dt)
#pragma unroll
                for (int r = 0; r < 16; ++r) oacc[dt][r] *= corr;
            mrun = mnew;
        }
        float rs = 0.f;
#pragma unroll
        for (int ss = 0; ss < 2; ++ss)
#pragma unroll
            for (int r = 0; r < 16; ++r) {
                const float p = exp2f(st[ss][r] - mrun);
                st[ss][r] = p;
                rs += p;
            }
        rs += __shfl_xor(rs, 32);
        lrun += rs;

        unsigned pk[2][8];
#pragma unroll
        for (int ss = 0; ss < 2; ++ss)
#pragma unroll
            for (int m = 0; m < 8; ++m)
                pk[ss][m] = pk_bf16(st[ss][2 * m], st[ss][2 * m + 1]);
#pragma unroll
        for (int kq = 0; kq < 4; ++kq) {
            const int ss = kq >> 1, A4 = (kq & 1) * 4;
            unsigned p0 = pk[ss][A4], p1 = pk[ss][A4+1], p2 = pk[ss][A4+2], p3 = pk[ss][A4+3];
            unsigned xp0 = __shfl_xor((int)p0, 32);
            unsigned xp1 = __shfl_xor((int)p1, 32);
            unsigned xp2 = __shfl_xor((int)p2, 32);
            unsigned xp3 = __shfl_xor((int)p3, 32);
            unsigned pf[4];
            pf[0] = h ? xp2 : p0;
            pf[1] = h ? xp3 : p1;
            pf[2] = h ? p2  : xp0;
            pf[3] = h ? p3  : xp1;
            const bf16x8 pfr = *(const bf16x8*)&pf[0];
#pragma unroll
            for (int dt = 0; dt < 2; ++dt) {
                const int pos = (kq * 2 + h) ^ (c31 & 7);
                bf16x8 vf = *(const bf16x8*)&Vt[buf][(dt * 32 + c31) * 64 + pos * 8];
                oacc[dt] = __builtin_amdgcn_mfma_f32_32x32x16_bf16(vf, pfr, oacc[dt], 0, 0, 0);
            }
        }
    }

    const float inv = 1.f / lrun;
    float* op = O + ((size_t)(b * LQ_ + q0 + c31)) * D_;
#pragma unroll
    for (int dt = 0; dt < 2; ++dt)
#pragma unroll
        for (int g = 0; g < 4; ++g) {
            f32x4 v;
#pragma unroll
            for (int j = 0; j < 4; ++j) v[j] = oacc[dt][4 * g + j] * inv;
            *(f32x4*)(op + dt * 32 + 8 * g + 4 * h) = v;
        }
}

extern "C" void kernel_launch(void* const* d_in, const int* in_sizes, int n_in,
                              void* d_out, int out_size, void* d_ws, size_t ws_size,
                              hipStream_t stream) {
    const float* Q    = (const float*)d_in[0];
    const float* K    = (const float*)d_in[1];
    const float* V    = (const float*)d_in[2];
    const int*   vlen = (const int*)d_in[3];
    float*       O    = (float*)d_out;

    const size_t rows = (size_t)B_ * LQ_;
    auto need = [&](int ns) { return (size_t)ns * rows * (D_ + 2) * sizeof(float); };

    int NS = 0;
    if      (d_ws && ws_size >= need(4)) NS = 4;
    else if (d_ws && ws_size >= need(2)) NS = 2;
    else if (d_ws && ws_size >= need(1)) NS = 1;

    if (NS == 0) {
        dim3 grid(LQ_ / 64, B_);
        fa_mono_kernel<<<grid, dim3(128), 0, stream>>>(Q, K, V, vlen, O);
        return;
    }

    float* OP = (float*)d_ws;
    float* ML = (float*)d_ws + (size_t)NS * rows * D_;

    const unsigned nblk = (unsigned)(16 * B_ * NS);   // 1D, LPT-ordered
    switch (NS) {
        case 4: fa_split7_kernel<4><<<dim3(nblk), dim3(256), 0, stream>>>(Q, K, V, vlen, OP, ML); break;
        case 2: fa_split7_kernel<2><<<dim3(nblk), dim3(256), 0, stream>>>(Q, K, V, vlen, OP, ML); break;
        default: fa_split7_kernel<1><<<dim3(nblk), dim3(256), 0, stream>>>(Q, K, V, vlen, OP, ML); break;
    }

    dim3 g2((unsigned)((rows * (D_ / 4)) / 256));   // 4096 blocks
    switch (NS) {
        case 4: fa_merge_kernel<4><<<g2, dim3(256), 0, stream>>>(OP, ML, O); break;
        case 2: fa_merge_kernel<2><<<g2, dim3(256), 0, stream>>>(OP, ML, O); break;
        default: fa_merge_kernel<1><<<g2, dim3(256), 0, stream>>>(OP, ML, O); break;
    }
}

// Round 11
// 152.063 us; speedup vs baseline: 1.0239x; 1.0239x over previous
//
#include <hip/hip_runtime.h>
#include <hip/hip_bf16.h>
#include <math.h>

// Masked dot-product attention, bf16 MFMA flash kernel, round 14.
// B=32, LQ=LK=2048, D=64. S^T = K*Q^T and O^T = V^T*P^T with 32x32x16 MFMA.
// = round 12 body + LDS-free LPT rank ONLY.
//  - Round-13 post-mortem: bundled {LDS-free rank, staging reorder, setprio}
//    regressed 66->78.8us with occupancy UP (27%) and VALUBusy/MfmaUtil DOWN
//    -> per-wave issue rate fell. Suspect setprio (m190: hurts barrier-synced
//    lockstep; our 4-wave blocks barrier every tile) and the staging reorder
//    (both orderings drain at the barrier's vmcnt(0); reorder just lengthens
//    live ranges). Both reverted.
//  - Kept: shfl+ballot LPT rank (verified by r13 counters: LDS_Block_Size
//    32768 -> 5 blocks/CU cap restored, occupancy 25.5->27).

#define B_    32
#define LQ_   2048
#define LK_   2048
#define D_    64

typedef __attribute__((ext_vector_type(8)))  short bf16x8;
typedef __attribute__((ext_vector_type(4)))  float f32x4;
typedef __attribute__((ext_vector_type(16))) float f32x16;
typedef __attribute__((ext_vector_type(2)))  unsigned u32x2;

static __device__ __forceinline__ unsigned pk_bf16(float a, float b) {
    __hip_bfloat162 h = __float22bfloat162_rn(float2{a, b});
    return *(unsigned*)&h;   // x in low 16 bits, y in high
}

// v_permlane32_swap_b32 via builtin (hazard-safe). Semantics: swaps the high
// 32 lanes of the first operand with the low 32 lanes of the second.
// r[0] = {a.lanes[0:31], b.lanes[0:31]}, r[1] = {a.lanes[32:63], b.lanes[32:63]}.
static __device__ __forceinline__ u32x2 plswap(unsigned a, unsigned b) {
    return __builtin_amdgcn_permlane32_swap(a, b, false, false);
}
// cross-half (lane ^ 32) reduce helpers (orientation-invariant: a == b)
static __device__ __forceinline__ float xhalf_max(float x) {
    u32x2 r = plswap(__float_as_uint(x), __float_as_uint(x));
    return fmaxf(__uint_as_float(r[0]), __uint_as_float(r[1]));
}
static __device__ __forceinline__ float xhalf_add(float x) {
    u32x2 r = plswap(__float_as_uint(x), __float_as_uint(x));
    return __uint_as_float(r[0]) + __uint_as_float(r[1]);
}

// ---------------------------------------------------------------------------
// Pass 1: per-(qblock=128 rows, batch, split) flash attention over [t0, t1).
// 256 threads = 4 q-waves sharing one double-buffered 64x64 K/V LDS tile.
// LPT: blockIdx.x -> (batch_rank, qblock, split); batch = rank-th longest vl,
// computed per-wave with shfl+ballot (no LDS, no barrier).
// Writes UNNORMALIZED O^T partial + (m, l) per q row.
// ---------------------------------------------------------------------------
template<int NS>
__global__ __launch_bounds__(256, 2) void fa_split8_kernel(
    const float* __restrict__ Q, const float* __restrict__ K,
    const float* __restrict__ V, const int* __restrict__ vlen,
    float* __restrict__ OP, float* __restrict__ ML)
{
    __shared__ __align__(16) short Kl[2][64 * 64];
    __shared__ __align__(16) short Vt[2][64 * 64];

    const int tid  = threadIdx.x;          // 0..255
    const int wid  = tid >> 6;             // 0..3  (q sub-block)
    const int lane = tid & 63;
    const int c31  = lane & 31;
    const int h    = lane >> 5;

    // ---- LPT remap (LDS-free): rank batches by vl DESC, index tie-break ----
    constexpr int PB = 16 * NS;            // blocks per batch (16,32,64)
    const int L    = blockIdx.x;
    const int rank = L / PB;               // compile-time divisor
    const int sub  = L % PB;
    const int qb   = sub & 15;
    const int s    = sub >> 4;
    int b;
    {
        const int vj = vlen[c31];          // lanes j and j+32 hold vlen[j]
        int r = 0;
#pragma unroll
        for (int k = 0; k < 32; ++k) {
            const int vk = __shfl(vj, k);  // broadcast vlen[k]
            r += (vk > vj) || (vk == vj && k < c31);
        }
        const unsigned long long match = __ballot(r == rank);
        b = (int)(__ffsll((unsigned long long)match) - 1) & 31;
    }
    const int q0 = qb * 128 + wid * 32;
    const int vl = vlen[b];
    const int nt    = (vl + 63) >> 6;
    const int chunk = (nt + NS - 1) / NS;
    const int t0    = s * chunk;
    const int t1    = min(t0 + chunk, nt);

    const float qscale = 0.125f * 1.44269504088896340736f;  // 1/sqrt(64)*log2(e)

    // ---- Q B-frags in registers: B[k=dim][n=q], dim = ks*16 + h*8 + j ----
    unsigned qfrag[4][4];
#pragma unroll
    for (int ks = 0; ks < 4; ++ks) {
        const float* qp = Q + ((size_t)(b * LQ_ + q0 + c31)) * D_ + ks * 16 + h * 8;
        f32x4 t0v = *(const f32x4*)qp;
        f32x4 t1v = *(const f32x4*)(qp + 4);
#pragma unroll
        for (int jj = 0; jj < 2; ++jj) {
            qfrag[ks][jj]     = pk_bf16(t0v[2*jj] * qscale, t0v[2*jj+1] * qscale);
            qfrag[ks][jj + 2] = pk_bf16(t1v[2*jj] * qscale, t1v[2*jj+1] * qscale);
        }
    }

    f32x16 oacc[2];     // O^T acc: dim row = dt*32 + (r&3)+8*(r>>2)+4h, col q = c31
#pragma unroll
    for (int dt = 0; dt < 2; ++dt)
#pragma unroll
        for (int r = 0; r < 16; ++r) oacc[dt][r] = 0.f;
    float mrun = -INFINITY, lrun = 0.f;

    // ---- staging maps (256 threads stage the whole 64x64 K and V tiles) ----
    const int skey = tid >> 2, skh = tid & 3;          // K: quarter-row each
    const int vkg = tid >> 4, vdg = tid & 15;          // V: 4 keys x 4 dims

    const float* kgp = K + ((size_t)(b * LK_ + skey)) * D_ + skh * 16;
    const float* vgp = V + ((size_t)(b * LK_ + vkg * 4)) * D_ + vdg * 4;

    f32x4 kr[4], vr[4];
    // ---- prologue: prefetch tile t0 into registers ----
    if (t0 < t1) {
        const size_t off = (size_t)t0 * 64 * D_;
#pragma unroll
        for (int i = 0; i < 4; ++i) kr[i] = *(const f32x4*)(kgp + off + 4 * i);
#pragma unroll
        for (int i = 0; i < 4; ++i) vr[i] = *(const f32x4*)(vgp + off + (size_t)i * D_);
    }

    for (int t = t0; t < t1; ++t) {
        const int k0 = t * 64;
        const int buf = t & 1;

        // ---- cvt + write tile t to LDS (round-12 ordering) ----
        {
            unsigned pk32[8];
#pragma unroll
            for (int m = 0; m < 8; ++m)
                pk32[m] = pk_bf16(kr[m >> 1][2 * (m & 1)], kr[m >> 1][2 * (m & 1) + 1]);
#pragma unroll
            for (int cch = 0; cch < 2; ++cch) {
                const int pos = (skh * 2 + cch) ^ (skey & 7);
                *(bf16x8*)&Kl[buf][skey * 64 + pos * 8] = *(bf16x8*)&pk32[4 * cch];
            }
#pragma unroll
            for (int dr = 0; dr < 4; ++dr) {
                const unsigned w0 = pk_bf16(vr[0][dr], vr[1][dr]);
                const unsigned w1 = pk_bf16(vr[2][dr], vr[3][dr]);
                const int dim = vdg * 4 + dr;
                const int pos = (vkg >> 1) ^ (dim & 7);
                uint2* dst = (uint2*)&Vt[buf][dim * 64 + pos * 8 + (vkg & 1) * 4];
                *dst = uint2{w0, w1};
            }
        }
        // ---- issue prefetch for tile t+1 (in flight until the barrier) ----
        if (t + 1 < t1) {
            const float* kn = kgp + (size_t)(k0 + 64) * D_;
            const float* vn = vgp + (size_t)(k0 + 64) * D_;
#pragma unroll
            for (int i = 0; i < 4; ++i) kr[i] = *(const f32x4*)(kn + 4 * i);
#pragma unroll
            for (int i = 0; i < 4; ++i) vr[i] = *(const f32x4*)(vn + (size_t)i * D_);
        }
        __syncthreads();

        // ---- S^T = K * Q^T : 2 key-tiles x 4 k-steps of 32x32x16 ----
        f32x16 st[2];
#pragma unroll
        for (int ss = 0; ss < 2; ++ss) {
#pragma unroll
            for (int r = 0; r < 16; ++r) st[ss][r] = 0.f;
#pragma unroll
            for (int ks = 0; ks < 4; ++ks) {
                const int pos = (ks * 2 + h) ^ (c31 & 7);
                bf16x8 kf = *(const bf16x8*)&Kl[buf][(ss * 32 + c31) * 64 + pos * 8];
                st[ss] = __builtin_amdgcn_mfma_f32_32x32x16_bf16(
                    kf, *(const bf16x8*)&qfrag[ks][0], st[ss], 0, 0, 0);
            }
        }

        // ---- mask tail keys >= vl ----
        if (k0 + 64 > vl) {
#pragma unroll
            for (int ss = 0; ss < 2; ++ss) {
                const int base = k0 + ss * 32 + 4 * h;
#pragma unroll
                for (int r = 0; r < 16; ++r) {
                    const int key = base + (r & 3) + 8 * (r >> 2);
                    if (key >= vl) st[ss][r] = -1e30f;
                }
            }
        }

        // ---- online softmax (log2 domain), defer-max; tree reductions ----
        float m8[8];
#pragma unroll
        for (int r = 0; r < 8; ++r)
            m8[r] = fmaxf(fmaxf(st[0][r], st[0][r + 8]),
                          fmaxf(st[1][r], st[1][r + 8]));
#pragma unroll
        for (int o = 4; o; o >>= 1)
#pragma unroll
            for (int r = 0; r < o; ++r) m8[r] = fmaxf(m8[r], m8[r + o]);
        const float tm = xhalf_max(m8[0]);

        if (__any(tm > mrun + 8.f)) {          // rare after the first tile
            const float mnew = fmaxf(mrun, tm);
            const float corr = exp2f(mrun - mnew);
            lrun *= corr;
#pragma unroll
            for (int dt = 0; dt < 2; ++dt)
#pragma unroll
                for (int r = 0; r < 16; ++r) oacc[dt][r] *= corr;
            mrun = mnew;
        }
#pragma unroll
        for (int ss = 0; ss < 2; ++ss)
#pragma unroll
            for (int r = 0; r < 16; ++r)
                st[ss][r] = exp2f(st[ss][r] - mrun);   // bounded by 2^8
        float s8[8];
#pragma unroll
        for (int r = 0; r < 8; ++r)
            s8[r] = (st[0][r] + st[0][r + 8]) + (st[1][r] + st[1][r + 8]);
#pragma unroll
        for (int o = 4; o; o >>= 1)
#pragma unroll
            for (int r = 0; r < o; ++r) s8[r] += s8[r + o];
        lrun += xhalf_add(s8[0]);

        // ---- pack P to bf16 pairs ----
        unsigned pk[2][8];
#pragma unroll
        for (int ss = 0; ss < 2; ++ss)
#pragma unroll
            for (int m = 0; m < 8; ++m)
                pk[ss][m] = pk_bf16(st[ss][2 * m], st[ss][2 * m + 1]);

        // ---- O^T += V^T * P^T : 4 k-steps x 2 dim-tiles ----
        //  P fragment exchange: r = plswap(p0, p2) -> r[0] = {p0.low, p2.low}
        //  = pf0, r[1] = {p0.high, p2.high} = pf2.
#pragma unroll
        for (int kq = 0; kq < 4; ++kq) {
            const int ss = kq >> 1, A4 = (kq & 1) * 4;
            u32x2 r02 = plswap(pk[ss][A4],     pk[ss][A4 + 2]);
            u32x2 r13 = plswap(pk[ss][A4 + 1], pk[ss][A4 + 3]);
            unsigned pf[4] = {r02[0], r13[0], r02[1], r13[1]};
            const bf16x8 pfr = *(const bf16x8*)&pf[0];
#pragma unroll
            for (int dt = 0; dt < 2; ++dt) {
                const int pos = (kq * 2 + h) ^ (c31 & 7);
                bf16x8 vf = *(const bf16x8*)&Vt[buf][(dt * 32 + c31) * 64 + pos * 8];
                oacc[dt] = __builtin_amdgcn_mfma_f32_32x32x16_bf16(vf, pfr, oacc[dt], 0, 0, 0);
            }
        }
    }

    // ---- epilogue: store UNNORMALIZED partial O^T and (m, l) ----
    const size_t row = (size_t)s * (B_ * LQ_) + b * LQ_ + q0 + c31;
    float* op = OP + row * D_;
#pragma unroll
    for (int dt = 0; dt < 2; ++dt)
#pragma unroll
        for (int g = 0; g < 4; ++g) {
            f32x4 v;
#pragma unroll
            for (int j = 0; j < 4; ++j) v[j] = oacc[dt][4 * g + j];
            *(f32x4*)(op + dt * 32 + 8 * g + 4 * h) = v;
        }
    if (h == 0)
        *(float2*)&ML[row * 2] = float2{mrun, lrun};   // (-inf, 0) if empty split
}

// ---------------------------------------------------------------------------
// Pass 2: merge NS partials per q row. One thread per (row, 4-dim chunk).
// ---------------------------------------------------------------------------
template<int NS>
__global__ __launch_bounds__(256) void fa_merge_kernel(
    const float* __restrict__ OP, const float* __restrict__ ML,
    float* __restrict__ O)
{
    const int g   = blockIdx.x * 256 + threadIdx.x;   // 0 .. B*LQ*16-1
    const int row = g >> 4;                            // b*LQ + q
    const int qd  = (g & 15) * 4;

    float mf = -INFINITY;
#pragma unroll
    for (int s = 0; s < NS; ++s) {
        float2 ml = *(const float2*)&ML[((size_t)s * (B_ * LQ_) + row) * 2];
        mf = fmaxf(mf, ml.x);                          // split 0 always finite
    }
    float den = 0.f;
    f32x4 acc = {0.f, 0.f, 0.f, 0.f};
#pragma unroll
    for (int s = 0; s < NS; ++s) {
        const size_t srow = (size_t)s * (B_ * LQ_) + row;
        float2 ml = *(const float2*)&ML[srow * 2];
        const float c = exp2f(ml.x - mf);              // 0 for empty splits
        den += c * ml.y;
        f32x4 v = *(const f32x4*)&OP[srow * D_ + qd];
        acc += v * c;                                  // empty split: c=0, v=0
    }
    const float inv = 1.f / den;
    *(f32x4*)(O + (size_t)row * D_ + qd) = acc * inv;
}

// ---------------------------------------------------------------------------
// Fallback: monolithic kernel (round-3 structure + defer-max), no workspace.
// ---------------------------------------------------------------------------
__global__ __launch_bounds__(128, 2) void fa_mono_kernel(
    const float* __restrict__ Q, const float* __restrict__ K,
    const float* __restrict__ V, const int* __restrict__ vlen,
    float* __restrict__ O)
{
    __shared__ __align__(16) short Kl[2][64 * 64];
    __shared__ __align__(16) short Vt[2][64 * 64];

    const int tid  = threadIdx.x;
    const int wave = tid >> 6;
    const int lane = tid & 63;
    const int c31  = lane & 31;
    const int h    = lane >> 5;

    const int b  = blockIdx.y;
    const int q0 = blockIdx.x * 64 + wave * 32;
    const int vl = vlen[b];
    const int nt = (vl + 63) >> 6;

    const float qscale = 0.125f * 1.44269504088896340736f;

    unsigned qfrag[4][4];
#pragma unroll
    for (int ks = 0; ks < 4; ++ks) {
        const float* qp = Q + ((size_t)(b * LQ_ + q0 + c31)) * D_ + ks * 16 + h * 8;
        f32x4 t0 = *(const f32x4*)qp;
        f32x4 t1 = *(const f32x4*)(qp + 4);
#pragma unroll
        for (int jj = 0; jj < 2; ++jj) {
            qfrag[ks][jj]     = pk_bf16(t0[2*jj] * qscale, t0[2*jj+1] * qscale);
            qfrag[ks][jj + 2] = pk_bf16(t1[2*jj] * qscale, t1[2*jj+1] * qscale);
        }
    }

    f32x16 oacc[2];
#pragma unroll
    for (int dt = 0; dt < 2; ++dt)
#pragma unroll
        for (int r = 0; r < 16; ++r) oacc[dt][r] = 0.f;
    float mrun = -INFINITY, lrun = 0.f;

    const int skey = tid >> 1, skh = tid & 1;
    const int vkg = tid >> 4, vdg = tid & 15;

    const float* kgp = K + ((size_t)(b * LK_ + skey)) * D_ + skh * 32;
    const float* vgp = V + ((size_t)(b * LK_ + vkg * 8)) * D_ + vdg * 4;

    f32x4 kr[8], vr[8];
#pragma unroll
    for (int i = 0; i < 8; ++i) kr[i] = *(const f32x4*)(kgp + 4 * i);
#pragma unroll
    for (int i = 0; i < 8; ++i) vr[i] = *(const f32x4*)(vgp + (size_t)i * D_);

    for (int t = 0; t < nt; ++t) {
        const int k0 = t * 64;
        const int buf = t & 1;
        {
            unsigned pk32[16];
#pragma unroll
            for (int m = 0; m < 16; ++m)
                pk32[m] = pk_bf16(kr[m >> 1][2 * (m & 1)], kr[m >> 1][2 * (m & 1) + 1]);
#pragma unroll
            for (int cch = 0; cch < 4; ++cch) {
                const int pos = (skh * 4 + cch) ^ (skey & 7);
                *(bf16x8*)&Kl[buf][skey * 64 + pos * 8] = *(bf16x8*)&pk32[4 * cch];
            }
#pragma unroll
            for (int dr = 0; dr < 4; ++dr) {
                unsigned w[4];
#pragma unroll
                for (int p = 0; p < 4; ++p)
                    w[p] = pk_bf16(vr[2 * p][dr], vr[2 * p + 1][dr]);
                const int dim = vdg * 4 + dr;
                const int pos = vkg ^ (dim & 7);
                *(bf16x8*)&Vt[buf][dim * 64 + pos * 8] = *(bf16x8*)&w[0];
            }
        }
        if (t + 1 < nt) {
            const float* kn = kgp + (size_t)(k0 + 64) * D_;
            const float* vn = vgp + (size_t)(k0 + 64) * D_;
#pragma unroll
            for (int i = 0; i < 8; ++i) kr[i] = *(const f32x4*)(kn + 4 * i);
#pragma unroll
            for (int i = 0; i < 8; ++i) vr[i] = *(const f32x4*)(vn + (size_t)i * D_);
        }
        __syncthreads();

        f32x16 st[2];
#pragma unroll
        for (int ss = 0; ss < 2; ++ss) {
#pragma unroll
            for (int r = 0; r < 16; ++r) st[ss][r] = 0.f;
#pragma unroll
            for (int ks = 0; ks < 4; ++ks) {
                const int pos = (ks * 2 + h) ^ (c31 & 7);
                bf16x8 kf = *(const bf16x8*)&Kl[buf][(ss * 32 + c31) * 64 + pos * 8];
                st[ss] = __builtin_amdgcn_mfma_f32_32x32x16_bf16(
                    kf, *(const bf16x8*)&qfrag[ks][0], st[ss], 0, 0, 0);
            }
        }
        if (k0 + 64 > vl) {
#pragma unroll
            for (int ss = 0; ss < 2; ++ss) {
                const int base = k0 + ss * 32 + 4 * h;
#pragma unroll
                for (int r = 0; r < 16; ++r) {
                    const int key = base + (r & 3) + 8 * (r >> 2);
                    if (key >= vl) st[ss][r] = -1e30f;
                }
            }
        }
        float tm = st[0][0];
#pragma unroll
        for (int ss = 0; ss < 2; ++ss)
#pragma unroll
            for (int r = 0; r < 16; ++r) tm = fmaxf(tm, st[ss][r]);
        tm = fmaxf(tm, __shfl_xor(tm, 32));
        if (__any(tm > mrun + 8.f)) {
            const float mnew = fmaxf(mrun, tm);
            const float corr = exp2f(mrun - mnew);
            lrun *= corr;
#pragma unroll
            for (int dt = 0; dt < 2; ++dt)
#pragma unroll
                for (int r = 0; r < 16; ++r) oacc[dt][r] *= corr;
            mrun = mnew;
        }
        float rs = 0.f;
#pragma unroll
        for (int ss = 0; ss < 2; ++ss)
#pragma unroll
            for (int r = 0; r < 16; ++r) {
                const float p = exp2f(st[ss][r] - mrun);
                st[ss][r] = p;
                rs += p;
            }
        rs += __shfl_xor(rs, 32);
        lrun += rs;

        unsigned pk[2][8];
#pragma unroll
        for (int ss = 0; ss < 2; ++ss)
#pragma unroll
            for (int m = 0; m < 8; ++m)
                pk[ss][m] = pk_bf16(st[ss][2 * m], st[ss][2 * m + 1]);
#pragma unroll
        for (int kq = 0; kq < 4; ++kq) {
            const int ss = kq >> 1, A4 = (kq & 1) * 4;
            unsigned p0 = pk[ss][A4], p1 = pk[ss][A4+1], p2 = pk[ss][A4+2], p3 = pk[ss][A4+3];
            unsigned xp0 = __shfl_xor((int)p0, 32);
            unsigned xp1 = __shfl_xor((int)p1, 32);
            unsigned xp2 = __shfl_xor((int)p2, 32);
            unsigned xp3 = __shfl_xor((int)p3, 32);
            unsigned pf[4];
            pf[0] = h ? xp2 : p0;
            pf[1] = h ? xp3 : p1;
            pf[2] = h ? p2  : xp0;
            pf[3] = h ? p3  : xp1;
            const bf16x8 pfr = *(const bf16x8*)&pf[0];
#pragma unroll
            for (int dt = 0; dt < 2; ++dt) {
                const int pos = (kq * 2 + h) ^ (c31 & 7);
                bf16x8 vf = *(const bf16x8*)&Vt[buf][(dt * 32 + c31) * 64 + pos * 8];
                oacc[dt] = __builtin_amdgcn_mfma_f32_32x32x16_bf16(vf, pfr, oacc[dt], 0, 0, 0);
            }
        }
    }

    const float inv = 1.f / lrun;
    float* op = O + ((size_t)(b * LQ_ + q0 + c31)) * D_;
#pragma unroll
    for (int dt = 0; dt < 2; ++dt)
#pragma unroll
        for (int g = 0; g < 4; ++g) {
            f32x4 v;
#pragma unroll
            for (int j = 0; j < 4; ++j) v[j] = oacc[dt][4 * g + j] * inv;
            *(f32x4*)(op + dt * 32 + 8 * g + 4 * h) = v;
        }
}

extern "C" void kernel_launch(void* const* d_in, const int* in_sizes, int n_in,
                              void* d_out, int out_size, void* d_ws, size_t ws_size,
                              hipStream_t stream) {
    const float* Q    = (const float*)d_in[0];
    const float* K    = (const float*)d_in[1];
    const float* V    = (const float*)d_in[2];
    const int*   vlen = (const int*)d_in[3];
    float*       O    = (float*)d_out;

    const size_t rows = (size_t)B_ * LQ_;
    auto need = [&](int ns) { return (size_t)ns * rows * (D_ + 2) * sizeof(float); };

    int NS = 0;
    if      (d_ws && ws_size >= need(4)) NS = 4;
    else if (d_ws && ws_size >= need(2)) NS = 2;
    else if (d_ws && ws_size >= need(1)) NS = 1;

    if (NS == 0) {
        dim3 grid(LQ_ / 64, B_);
        fa_mono_kernel<<<grid, dim3(128), 0, stream>>>(Q, K, V, vlen, O);
        return;
    }

    float* OP = (float*)d_ws;
    float* ML = (float*)d_ws + (size_t)NS * rows * D_;

    const unsigned nblk = (unsigned)(16 * B_ * NS);   // 1D, LPT-ordered
    switch (NS) {
        case 4: fa_split8_kernel<4><<<dim3(nblk), dim3(256), 0, stream>>>(Q, K, V, vlen, OP, ML); break;
        case 2: fa_split8_kernel<2><<<dim3(nblk), dim3(256), 0, stream>>>(Q, K, V, vlen, OP, ML); break;
        default: fa_split8_kernel<1><<<dim3(nblk), dim3(256), 0, stream>>>(Q, K, V, vlen, OP, ML); break;
    }

    dim3 g2((unsigned)((rows * (D_ / 4)) / 256));   // 4096 blocks
    switch (NS) {
        case 4: fa_merge_kernel<4><<<g2, dim3(256), 0, stream>>>(OP, ML, O); break;
        case 2: fa_merge_kernel<2><<<g2, dim3(256), 0, stream>>>(OP, ML, O); break;
        default: fa_merge_kernel<1><<<g2, dim3(256), 0, stream>>>(OP, ML, O); break;
    }
}